// Round 5
// baseline (350.822 us; speedup 1.0000x reference)
//
#include <hip/hip_runtime.h>

typedef unsigned short ushort_t;
typedef unsigned int uint_t;
typedef __bf16 bf16x8 __attribute__((ext_vector_type(8)));
typedef float f32x4 __attribute__((ext_vector_type(4)));

#define B_ROWS 65536

// Tile geometry: one MFMA tile = 16 rows x 32 k of bf16 = 1024 B = 512 ushorts.
// Unit l (0..63) within a tile <-> (row = l&15, k = (l>>4)*8 .. +8).
#define KT1 12    // K1 k-iters  (K 376 -> 384)
#define NT1 30    // K1 n-tiles  (N 400 -> 480)
#define KTC1 15   // h1' k-tiles (480/32)
#define KI2 13    // K2 k-iters  (K 400 -> 416; h1' cols 400..480 are exact 0)
#define NT2 20    // K2 n-tiles  (N 320)
#define KTC2 10   // h2' k-tiles (320/32)
#define KI3 10    // K3 k-iters  (320/32)
#define NT3 50    // K3 n-tiles  (N 800: aligned head layout)
#define KTH 25    // heads' row-stride in ktiles (800/32)

// Aligned head layout (all slots on 8-col boundaries; pads are exact zeros):
//  [0:24)  mu (17 real)   groups 0..2
//  [24:48) lv (17 real)   groups 3..5
//  [48:64) b  (15 real)   groups 6..7
//  [64+48k : +24)  u_k (17 real)  groups 8+6k .. +2
//  [64+48k+24 : +48) w_k (17 real) groups 11+6k .. +2

#define SZ1 (NT1 * KT1 * 512)
#define SZ2 (NT2 * KI2 * 512)
#define SZ3 (NT3 * KI3 * 512)

// workspace (ushort units): [h2'][h1' -> overlaid by heads][weights]
#define H2_US    ((size_t)4096 * KTC2 * 512)
#define HEADS_US ((size_t)4096 * KTH * 512)

__device__ inline ushort_t f2bf(float f) {
    uint_t u = __float_as_uint(f);
    return (ushort_t)((u + 0x7FFFu + ((u >> 16) & 1u)) >> 16);
}
__device__ inline uint_t pack2(float a, float b) {
    return (uint_t)f2bf(a) | ((uint_t)f2bf(b) << 16);
}
__device__ inline float fast_tanh(float x) {
    float e = __expf(2.f * x);
    return 1.f - 2.f / (e + 1.f);
}
// async global->LDS, 16 B per lane; LDS dest = wave-uniform base + lane*16
__device__ inline void gl2lds16(const ushort_t* g, ushort_t* l) {
    __builtin_amdgcn_global_load_lds(
        (const __attribute__((address_space(1))) uint_t*)g,
        (__attribute__((address_space(3))) uint_t*)l, 16, 0, 0);
}
__device__ inline void unpack8(uint4 v, float* dst) {
    uint_t q[4] = {v.x, v.y, v.z, v.w};
    #pragma unroll
    for (int m = 0; m < 4; ++m) {
        dst[2 * m]     = __uint_as_float(q[m] << 16);          // low bf16
        dst[2 * m + 1] = __uint_as_float(q[m] & 0xFFFF0000u);  // high bf16
    }
}

// ---------------------------------------------------------------------------
// pack_kernel: fp32 weights -> MFMA-tile-order bf16 + zero-padded fp32 biases.
// ---------------------------------------------------------------------------
__global__ void pack_kernel(const float* __restrict__ W1, const float* __restrict__ W2,
                            const float* __restrict__ Wmu, const float* __restrict__ Wlv,
                            const float* __restrict__ Wu, const float* __restrict__ Ww,
                            const float* __restrict__ Wb,
                            const float* __restrict__ b1, const float* __restrict__ b2,
                            const float* __restrict__ bmu, const float* __restrict__ blv,
                            const float* __restrict__ bu, const float* __restrict__ bw,
                            const float* __restrict__ bb,
                            ushort_t* __restrict__ W1t, ushort_t* __restrict__ W2t,
                            ushort_t* __restrict__ Wht,
                            float* __restrict__ b1p, float* __restrict__ b2p,
                            float* __restrict__ bHp)
{
    int i = blockIdx.x * 256 + threadIdx.x;
    if (i < SZ1) {
        int t = i >> 9, pos = i & 511;
        int l = pos >> 3, j = pos & 7;
        int n = (t / KT1) * 16 + (l & 15);
        int k = (t % KT1) * 32 + (l >> 4) * 8 + j;
        W1t[i] = (n < 400 && k < 376) ? f2bf(W1[k * 400 + n]) : (ushort_t)0;
    } else if (i < SZ1 + SZ2) {
        int i2 = i - SZ1;
        int t = i2 >> 9, pos = i2 & 511;
        int l = pos >> 3, j = pos & 7;
        int n = (t / KI2) * 16 + (l & 15);
        int k = (t % KI2) * 32 + (l >> 4) * 8 + j;
        W2t[i2] = (n < 300 && k < 400) ? f2bf(W2[k * 300 + n]) : (ushort_t)0;
    } else if (i < SZ1 + SZ2 + SZ3) {
        int i3 = i - SZ1 - SZ2;
        int t = i3 >> 9, pos = i3 & 511;
        int l = pos >> 3, j = pos & 7;
        int n = (t / KI3) * 16 + (l & 15);
        int k = (t % KI3) * 32 + (l >> 4) * 8 + j;
        float v = 0.f;
        if (k < 300) {
            if (n < 24)      { if (n < 17) v = Wmu[k * 17 + n]; }
            else if (n < 48) { int c = n - 24; if (c < 17) v = Wlv[k * 17 + c]; }
            else if (n < 64) { int c = n - 48; if (c < 15) v = Wb[k * 15 + c]; }
            else if (n < 784) {
                int r = n - 64, slot = r / 48, c = r % 48;
                if (c < 24) { if (c < 17) v = Wu[k * 255 + slot * 17 + c]; }
                else        { int c2 = c - 24; if (c2 < 17) v = Ww[k * 255 + slot * 17 + c2]; }
            }
        }
        Wht[i3] = f2bf(v);
    } else {
        int j = i - SZ1 - SZ2 - SZ3;
        if (j < 480) {
            b1p[j] = (j < 400) ? b1[j] : 0.f;
        } else if (j < 800) {
            int n = j - 480;
            b2p[n] = (n < 300) ? b2[n] : 0.f;
        } else if (j < 1600) {
            int n = j - 800;
            float v = 0.f;
            if (n < 24)      { if (n < 17) v = bmu[n]; }
            else if (n < 48) { int c = n - 24; if (c < 17) v = blv[c]; }
            else if (n < 64) { int c = n - 48; if (c < 15) v = bb[c]; }
            else if (n < 784) {
                int r = n - 64, slot = r / 48, c = r % 48;
                if (c < 24) { if (c < 17) v = bu[slot * 17 + c]; }
                else        { int c2 = c - 24; if (c2 < 17) v = bw[slot * 17 + c2]; }
            }
            bHp[n] = v;
        }
    }
}

// ---------------------------------------------------------------------------
// gemm_rs: C' = act(A @ B^T + bias).
//   A: per-lane register loads straight from global (NO LDS round-trip).
//      CVT_A=true: A is f32 x (row-major, ld 376), converted to bf16 in-reg.
//      CVT_A=false: A is bf16 tiled; lane l's MFMA A-frag == the 16 B at
//      unit l of the tile -> one uint4 load per rowtile.
//   B: double-buffered LDS via global_load_lds (weights, L2-resident).
// 512 thr = 8 waves: wave (wr = wv>>1, wc = wv&1) owns rowtiles {2wr,2wr+1}
// and ntiles [5wc, 5wc+5). BM=128, BN=160, BK=32. acc = 40 VGPR/lane.
// LDS = 20 KB. Target 4 waves/SIMD (2 blocks/CU) via __launch_bounds__(512,4).
// XCD-bijective remap keeps all NX n-blocks of a rowblock on one XCD (L2 A-reuse).
// ---------------------------------------------------------------------------
template<int KITERS, int NX, bool RELU, bool CVT_A>
__global__ __launch_bounds__(512, 4)
void gemm_rs(const ushort_t* __restrict__ At, const float* __restrict__ xf,
             const ushort_t* __restrict__ Bt, const float* __restrict__ bias,
             ushort_t* __restrict__ C, int kTA, int kTC)
{
    __shared__ ushort_t Bs[2][10 * 512];
    const int tid = threadIdx.x;
    const int lane = tid & 63, wv = tid >> 6;
    const int wr = wv >> 1, wc = wv & 1;
    const int q = lane >> 4, l16 = lane & 15;

    // bijective XCD remap (gridDim.x = NX*512; 512 % 8 == 0)
    const int b = blockIdx.x;
    const int xcd = b & 7, idx = b >> 3;
    const int grp = idx / NX;
    const int bx = idx - grp * NX;
    const int by = xcd + grp * 8;
    const int nb0 = bx * 10;
    const int rowblk0 = by * 8;

    f32x4 acc[2][5];
    #pragma unroll
    for (int r = 0; r < 2; ++r)
        #pragma unroll
        for (int c = 0; c < 5; ++c)
            acc[r][c] = (f32x4){0.f, 0.f, 0.f, 0.f};

    // per-lane A fragment loader (rowtiles 2wr, 2wr+1 at k-tile kt)
    auto loadA = [&](int kt, bf16x8* a) {
        #pragma unroll
        for (int r = 0; r < 2; ++r) {
            int rt = rowblk0 + wr * 2 + r;
            if (CVT_A) {
                int row = rt * 16 + l16;
                int k0 = kt * 32 + q * 8;
                uint4 o = {0u, 0u, 0u, 0u};
                if (k0 + 8 <= 376) {
                    const float4* p = reinterpret_cast<const float4*>(
                        xf + (size_t)row * 376 + k0);
                    float4 v0 = p[0], v1 = p[1];
                    o.x = pack2(v0.x, v0.y); o.y = pack2(v0.z, v0.w);
                    o.z = pack2(v1.x, v1.y); o.w = pack2(v1.z, v1.w);
                }
                a[r] = __builtin_bit_cast(bf16x8, o);
            } else {
                a[r] = __builtin_bit_cast(bf16x8, *reinterpret_cast<const uint4*>(
                    At + (((size_t)rt * kTA + kt) << 9) + lane * 8));
            }
        }
    };
    auto stageB = [&](int kt, int buf) {
        gl2lds16(Bt + (((size_t)(nb0 + wv) * KITERS + kt) << 9) + lane * 8,
                 &Bs[buf][wv << 9]);
        if (wv < 2)
            gl2lds16(Bt + (((size_t)(nb0 + 8 + wv) * KITERS + kt) << 9) + lane * 8,
                     &Bs[buf][(8 + wv) << 9]);
    };

    // ---- prologue ----
    stageB(0, 0);
    bf16x8 ac[2];
    loadA(0, ac);
    __syncthreads();

    // ---- main loop: compute buf p, stage kt+1 into buf p^1 ----
    #pragma unroll
    for (int kt = 0; kt < KITERS; ++kt) {
        const int p = kt & 1;
        bf16x8 an[2];
        if (kt + 1 < KITERS) {
            stageB(kt + 1, p ^ 1);
            loadA(kt + 1, an);
        }
        #pragma unroll
        for (int c = 0; c < 5; ++c) {
            bf16x8 bb = __builtin_bit_cast(bf16x8, *reinterpret_cast<const uint4*>(
                &Bs[p][((wc * 5 + c) << 9) + lane * 8]));
            acc[0][c] = __builtin_amdgcn_mfma_f32_16x16x32_bf16(ac[0], bb, acc[0][c], 0, 0, 0);
            acc[1][c] = __builtin_amdgcn_mfma_f32_16x16x32_bf16(ac[1], bb, acc[1][c], 0, 0, 0);
        }
        __syncthreads();
        if (kt + 1 < KITERS) { ac[0] = an[0]; ac[1] = an[1]; }
    }

    // ---- epilogue: bias + act -> tiled C; C/D frag: col=l16, row=q*4+reg ----
    #pragma unroll
    for (int r = 0; r < 2; ++r) {
        int rowblk = rowblk0 + wr * 2 + r;
        #pragma unroll
        for (int c = 0; c < 5; ++c) {
            int n = (nb0 + wc * 5 + c) * 16 + l16;
            float bv = bias[n];
            #pragma unroll
            for (int reg = 0; reg < 4; ++reg) {
                float v = acc[r][c][reg] + bv;
                if (RELU) v = fmaxf(v, 0.f);
                int mrow = q * 4 + reg;
                size_t off = (((size_t)rowblk * kTC + (n >> 5)) << 9)
                           + (size_t)(((n >> 3) & 3) * 16 + mrow) * 8 + (n & 7);
                C[off] = f2bf(v);
            }
        }
    }
}

// ---------------------------------------------------------------------------
// flow_kernel v3: 4 lanes per row (lane sub owns head cols [8*sub, 8*sub+8)).
// Aligned 48-col u/w slots -> one uint4 per lane per vector, fully coalesced.
// Dots reduced across the 4-lane group via shfl_xor(1,2). No LDS, no spills.
// ---------------------------------------------------------------------------
__device__ inline void ld_group8(const ushort_t* hb, int g, float* dst) {
    uint4 v = *reinterpret_cast<const uint4*>(hb + ((g >> 2) << 9) + ((g & 3) << 7));
    unpack8(v, dst);
}

__global__ __launch_bounds__(256, 4)
void flow_kernel(const ushort_t* __restrict__ heads, const float* __restrict__ eps,
                 float* __restrict__ out, int Btot)
{
    const int tid = threadIdx.x;
    const int sub = tid & 3;
    const long row = (long)blockIdx.x * 64 + (tid >> 2);
    const ushort_t* hb = heads + (((size_t)(row >> 4) * KTH) << 9)
                               + (size_t)((row & 15) << 3);

    float z[8];
    float lp = 0.f;
    {
        float amu[8] = {0,0,0,0,0,0,0,0}, alv[8] = {0,0,0,0,0,0,0,0};
        if (sub < 3) {
            ld_group8(hb, sub, amu);
            ld_group8(hb, 3 + sub, alv);
        }
        float ep[8];
        #pragma unroll
        for (int c = 0; c < 8; ++c) {
            int i = sub * 8 + c;
            ep[c] = (i < 17) ? eps[row * 17 + i] : 0.f;
        }
        #pragma unroll
        for (int c = 0; c < 8; ++c) {
            float mu = fast_tanh(amu[c]);
            float lv = fast_tanh(alv[c]);
            z[c] = mu + __expf(lv) * ep[c];
            int i = sub * 8 + c;
            lp += (i < 17) ? (-0.5f * ep[c] * ep[c] - lv - 0.918938533f) : 0.f;
        }
    }

    float bv[16];
    ld_group8(hb, 6, &bv[0]);
    ld_group8(hb, 7, &bv[8]);

    float ldj = 0.f;
    #pragma unroll
    for (int k = 0; k < 15; ++k) {
        float au[8] = {0,0,0,0,0,0,0,0}, aw[8] = {0,0,0,0,0,0,0,0};
        if (sub < 3) {
            ld_group8(hb, 8 + 6 * k + sub, au);
            ld_group8(hb, 11 + 6 * k + sub, aw);
        }
        float uw = 0.f, w2 = 0.f, wz = 0.f;
        #pragma unroll
        for (int c = 0; c < 8; ++c) {
            uw += aw[c] * au[c];
            w2 += aw[c] * aw[c];
            wz += aw[c] * z[c];
        }
        uw += __shfl_xor(uw, 1); uw += __shfl_xor(uw, 2);
        w2 += __shfl_xor(w2, 1); w2 += __shfl_xor(w2, 2);
        wz += __shfl_xor(wz, 1); wz += __shfl_xor(wz, 2);

        float sp = (uw > 15.f) ? uw : __logf(1.f + __expf(uw));
        float m = sp - 1.f;                          // -1 + softplus(w.u)
        float coef = (m - uw) / fmaxf(w2, 1e-20f);
        float t = fast_tanh(wz + bv[k]);
        #pragma unroll
        for (int c = 0; c < 8; ++c)
            z[c] += (au[c] + coef * aw[c]) * t;
        float psi = m * (1.f - t * t);               // psi^T u_hat == m analytically
        ldj += __logf(fmaxf(fabsf(1.f + psi), 1e-30f));
    }

    lp += __shfl_xor(lp, 1); lp += __shfl_xor(lp, 2);
    #pragma unroll
    for (int c = 0; c < 8; ++c) {
        int i = sub * 8 + c;
        if (i < 17) out[row * 17 + i] = z[c];
    }
    float lpf = lp - ldj;
    if (sub == 0) {
        out[(long)Btot * 17 + row] = __expf(lpf);
        out[(long)Btot * 18 + row] = lpf;
    }
}

// ---------------------------------------------------------------------------
extern "C" void kernel_launch(void* const* d_in, const int* in_sizes, int n_in,
                              void* d_out, int out_size, void* d_ws, size_t ws_size,
                              hipStream_t stream)
{
    const float* x   = (const float*)d_in[0];
    const float* eps = (const float*)d_in[1];
    float* out = (float*)d_out;

    // ws layout (ushort units):
    //  [0, H2_US)                 h2' tiled (stride KTC2)
    //  [H2_US, H2_US+HEADS_US)    h1' tiled (stride KTC1) then heads tiled
    //                             (stride KTH) -- h1' dead by K3
    //  weights after + biases
    ushort_t* ws = (ushort_t*)d_ws;
    ushort_t* R_h2    = ws;
    ushort_t* R_h1    = ws + H2_US;
    ushort_t* R_heads = ws + H2_US;        // overlays h1'
    ushort_t* W1t = ws + H2_US + HEADS_US;
    ushort_t* W2t = W1t + SZ1;
    ushort_t* Wht = W2t + SZ2;
    float* b1p = (float*)(Wht + SZ3);
    float* b2p = b1p + 480;
    float* bHp = b2p + 320;

    const int packN = SZ1 + SZ2 + SZ3 + 1600;
    pack_kernel<<<(packN + 255) / 256, 256, 0, stream>>>(
        (const float*)d_in[2],  (const float*)d_in[4],
        (const float*)d_in[6],  (const float*)d_in[8],
        (const float*)d_in[10], (const float*)d_in[12], (const float*)d_in[14],
        (const float*)d_in[3],  (const float*)d_in[5],
        (const float*)d_in[7],  (const float*)d_in[9],
        (const float*)d_in[11], (const float*)d_in[13], (const float*)d_in[15],
        W1t, W2t, Wht, b1p, b2p, bHp);

    // K1: h1' = relu(x @ W1^T + b1), cvt fused.  M=65536 K=384 N=480
    gemm_rs<KT1, 3, true, true><<<3 * 512, 512, 0, stream>>>(
        nullptr, x, W1t, b1p, R_h1, 0, KTC1);
    // K2: h2' = relu(h1' @ W2^T + b2).           M=65536 K=416 N=320
    gemm_rs<KI2, 2, true, false><<<2 * 512, 512, 0, stream>>>(
        R_h1, nullptr, W2t, b2p, R_h2, KTC1, KTC2);
    // K3: heads = h2' @ Wh^T + bH.               M=65536 K=320 N=800
    gemm_rs<KI3, 5, false, false><<<5 * 512, 512, 0, stream>>>(
        R_h2, nullptr, Wht, bHp, R_heads, KTC2, KTH);
    // K4: planar flow + log-prob
    flow_kernel<<<B_ROWS / 64, 256, 0, stream>>>(R_heads, eps, out, B_ROWS);
}

// Round 6
// 346.803 us; speedup vs baseline: 1.0116x; 1.0116x over previous
//
#include <hip/hip_runtime.h>

typedef unsigned short ushort_t;
typedef unsigned int uint_t;
typedef __bf16 bf16x8 __attribute__((ext_vector_type(8)));
typedef float f32x4 __attribute__((ext_vector_type(4)));

#define B_ROWS 65536

// Tile geometry: one MFMA tile = 16 rows x 32 k of bf16 = 1024 B = 512 ushorts.
// Unit l (0..63) within a tile <-> (row = l&15, k = (l>>4)*8 .. +8).
#define KT1 12    // K1 k-iters  (K 376 -> 384)
#define NT1 30    // K1 n-tiles  (N 400 -> 480)
#define KTC1 15   // h1' k-tiles (480/32)
#define KI2 13    // K2 k-iters  (K 400 -> 416; h1' cols 400..480 are exact 0)
#define NT2 20    // K2 n-tiles  (N 320)
#define KTC2 10   // h2' k-tiles (320/32)
#define KI3 10    // K3 k-iters  (320/32)
#define NT3 50    // K3 n-tiles  (N 800: aligned head layout)
#define KTH 25    // heads' row-stride in ktiles (800/32)

// Aligned head layout (all slots on 8-col boundaries; pads are exact zeros):
//  [0:24)  mu (17 real)   groups 0..2
//  [24:48) lv (17 real)   groups 3..5
//  [48:64) b  (15 real)   groups 6..7
//  [64+48k : +24)  u_k (17 real)  groups 8+6k .. +2
//  [64+48k+24 : +48) w_k (17 real) groups 11+6k .. +2

#define SZ1 (NT1 * KT1 * 512)
#define SZ2 (NT2 * KI2 * 512)
#define SZ3 (NT3 * KI3 * 512)

// workspace (ushort units): [h2'][h1' -> overlaid by heads][weights]
#define H2_US    ((size_t)4096 * KTC2 * 512)
#define HEADS_US ((size_t)4096 * KTH * 512)

__device__ inline ushort_t f2bf(float f) {
    uint_t u = __float_as_uint(f);
    return (ushort_t)((u + 0x7FFFu + ((u >> 16) & 1u)) >> 16);
}
__device__ inline uint_t pack2(float a, float b) {
    return (uint_t)f2bf(a) | ((uint_t)f2bf(b) << 16);
}
__device__ inline float fast_tanh(float x) {
    float e = __expf(2.f * x);
    return 1.f - 2.f / (e + 1.f);
}
// async global->LDS, 16 B per lane; LDS dest = wave-uniform base + lane*16
__device__ inline void gl2lds16(const ushort_t* g, ushort_t* l) {
    __builtin_amdgcn_global_load_lds(
        (const __attribute__((address_space(1))) uint_t*)g,
        (__attribute__((address_space(3))) uint_t*)l, 16, 0, 0);
}
__device__ inline void unpack8(uint4 v, float* dst) {
    uint_t q[4] = {v.x, v.y, v.z, v.w};
    #pragma unroll
    for (int m = 0; m < 4; ++m) {
        dst[2 * m]     = __uint_as_float(q[m] << 16);          // low bf16
        dst[2 * m + 1] = __uint_as_float(q[m] & 0xFFFF0000u);  // high bf16
    }
}

// ---------------------------------------------------------------------------
// pack_kernel: fp32 weights -> MFMA-tile-order bf16 + zero-padded fp32 biases.
// ---------------------------------------------------------------------------
__global__ void pack_kernel(const float* __restrict__ W1, const float* __restrict__ W2,
                            const float* __restrict__ Wmu, const float* __restrict__ Wlv,
                            const float* __restrict__ Wu, const float* __restrict__ Ww,
                            const float* __restrict__ Wb,
                            const float* __restrict__ b1, const float* __restrict__ b2,
                            const float* __restrict__ bmu, const float* __restrict__ blv,
                            const float* __restrict__ bu, const float* __restrict__ bw,
                            const float* __restrict__ bb,
                            ushort_t* __restrict__ W1t, ushort_t* __restrict__ W2t,
                            ushort_t* __restrict__ Wht,
                            float* __restrict__ b1p, float* __restrict__ b2p,
                            float* __restrict__ bHp)
{
    int i = blockIdx.x * 256 + threadIdx.x;
    if (i < SZ1) {
        int t = i >> 9, pos = i & 511;
        int l = pos >> 3, j = pos & 7;
        int n = (t / KT1) * 16 + (l & 15);
        int k = (t % KT1) * 32 + (l >> 4) * 8 + j;
        W1t[i] = (n < 400 && k < 376) ? f2bf(W1[k * 400 + n]) : (ushort_t)0;
    } else if (i < SZ1 + SZ2) {
        int i2 = i - SZ1;
        int t = i2 >> 9, pos = i2 & 511;
        int l = pos >> 3, j = pos & 7;
        int n = (t / KI2) * 16 + (l & 15);
        int k = (t % KI2) * 32 + (l >> 4) * 8 + j;
        W2t[i2] = (n < 300 && k < 400) ? f2bf(W2[k * 300 + n]) : (ushort_t)0;
    } else if (i < SZ1 + SZ2 + SZ3) {
        int i3 = i - SZ1 - SZ2;
        int t = i3 >> 9, pos = i3 & 511;
        int l = pos >> 3, j = pos & 7;
        int n = (t / KI3) * 16 + (l & 15);
        int k = (t % KI3) * 32 + (l >> 4) * 8 + j;
        float v = 0.f;
        if (k < 300) {
            if (n < 24)      { if (n < 17) v = Wmu[k * 17 + n]; }
            else if (n < 48) { int c = n - 24; if (c < 17) v = Wlv[k * 17 + c]; }
            else if (n < 64) { int c = n - 48; if (c < 15) v = Wb[k * 15 + c]; }
            else if (n < 784) {
                int r = n - 64, slot = r / 48, c = r % 48;
                if (c < 24) { if (c < 17) v = Wu[k * 255 + slot * 17 + c]; }
                else        { int c2 = c - 24; if (c2 < 17) v = Ww[k * 255 + slot * 17 + c2]; }
            }
        }
        Wht[i3] = f2bf(v);
    } else {
        int j = i - SZ1 - SZ2 - SZ3;
        if (j < 480) {
            b1p[j] = (j < 400) ? b1[j] : 0.f;
        } else if (j < 800) {
            int n = j - 480;
            b2p[n] = (n < 300) ? b2[n] : 0.f;
        } else if (j < 1600) {
            int n = j - 800;
            float v = 0.f;
            if (n < 24)      { if (n < 17) v = bmu[n]; }
            else if (n < 48) { int c = n - 24; if (c < 17) v = blv[c]; }
            else if (n < 64) { int c = n - 48; if (c < 15) v = bb[c]; }
            else if (n < 784) {
                int r = n - 64, slot = r / 48, c = r % 48;
                if (c < 24) { if (c < 17) v = bu[slot * 17 + c]; }
                else        { int c2 = c - 24; if (c2 < 17) v = bw[slot * 17 + c2]; }
            }
            bHp[n] = v;
        }
    }
}

// ---------------------------------------------------------------------------
// gemm_bp: C' = act(A @ B^T + bias) with the FULL B panel resident in LDS.
//   Stage all KITERS*10 B tiles once (one barrier), then the K-loop has
//   NO barriers: B via ds_read_b128 from the panel, A per-lane from global
//   with an explicit depth-4 prefetch ring (fully unrolled, static indices).
//   CVT_A=true: A is f32 x (row-major, ld 376), converted to bf16 in-reg.
// 512 thr = 8 waves: wave (wr = wv>>1, wc = wv&1) owns rowtiles {2wr,2wr+1}
// and ntiles [5wc, 5wc+5). BM=128, BN=160, BK=32. acc = 40 VGPR/lane.
// LDS = KITERS*10 KB (100..130 KB) -> 1 block/CU, 2 waves/SIMD; latency is
// hidden by ILP across the unrolled, barrier-free K-loop.
// XCD-bijective remap keeps all NX n-blocks of a rowblock on one XCD.
// ---------------------------------------------------------------------------
template<int KITERS, int NX, bool RELU, bool CVT_A>
__global__ __launch_bounds__(512, 2)
void gemm_bp(const ushort_t* __restrict__ At, const float* __restrict__ xf,
             const ushort_t* __restrict__ Bt, const float* __restrict__ bias,
             ushort_t* __restrict__ C, int kTA, int kTC)
{
    __shared__ ushort_t Bs[KITERS * 10 * 512];
    const int tid = threadIdx.x;
    const int lane = tid & 63, wv = tid >> 6;
    const int wr = wv >> 1, wc = wv & 1;
    const int q = lane >> 4, l16 = lane & 15;

    // bijective XCD remap (gridDim.x = NX*512; 512 % 8 == 0)
    const int b = blockIdx.x;
    const int xcd = b & 7, idx = b >> 3;
    const int grp = idx / NX;
    const int bx = idx - grp * NX;
    const int by = xcd + grp * 8;
    const int nb0 = bx * 10;
    const int rowblk0 = by * 8;

    // ---- stage the ENTIRE B panel: tiles t = n*KITERS+kt (global-contiguous),
    //      LDS layout [kt][n] so the K-loop reads are contiguous per kt ----
    for (int t = wv; t < KITERS * 10; t += 8) {
        int n = t / KITERS, kt = t - n * KITERS;
        gl2lds16(Bt + (((size_t)nb0 * KITERS + t) << 9) + lane * 8,
                 &Bs[(kt * 10 + n) << 9]);
    }

    // ---- A prefetch ring, depth 4 (fully unrolled -> static indices) ----
    constexpr int P = (KITERS < 4) ? KITERS : 4;
    float4 rawA[CVT_A ? KITERS : 1][4];   // CVT: raw f32 (2 float4 per rowtile)
    uint4  binA[CVT_A ? 1 : KITERS][2];   // tiled bf16: 1 uint4 per rowtile

    auto issueA = [&](int kt) {
        #pragma unroll
        for (int r = 0; r < 2; ++r) {
            int rt = rowblk0 + wr * 2 + r;
            if (CVT_A) {
                int row = rt * 16 + l16;
                int k0 = kt * 32 + q * 8;
                float4 lo = {0.f, 0.f, 0.f, 0.f}, hi = {0.f, 0.f, 0.f, 0.f};
                if (k0 + 8 <= 376) {
                    const float4* p = reinterpret_cast<const float4*>(
                        xf + (size_t)row * 376 + k0);
                    lo = p[0]; hi = p[1];
                }
                rawA[CVT_A ? kt : 0][2 * r] = lo;
                rawA[CVT_A ? kt : 0][2 * r + 1] = hi;
            } else {
                binA[CVT_A ? 0 : kt][r] = *reinterpret_cast<const uint4*>(
                    At + (((size_t)rt * kTA + kt) << 9) + lane * 8);
            }
        }
    };

    f32x4 acc[2][5];
    #pragma unroll
    for (int r = 0; r < 2; ++r)
        #pragma unroll
        for (int c = 0; c < 5; ++c)
            acc[r][c] = (f32x4){0.f, 0.f, 0.f, 0.f};

    #pragma unroll
    for (int i = 0; i < P; ++i) issueA(i);
    __syncthreads();   // the ONLY barrier: B panel (and prefetched A) ready

    // ---- barrier-free K-loop ----
    #pragma unroll
    for (int kt = 0; kt < KITERS; ++kt) {
        // consume slot kt
        bf16x8 a[2];
        #pragma unroll
        for (int r = 0; r < 2; ++r) {
            if (CVT_A) {
                float4 lo = rawA[CVT_A ? kt : 0][2 * r];
                float4 hi = rawA[CVT_A ? kt : 0][2 * r + 1];
                uint4 o;
                o.x = pack2(lo.x, lo.y); o.y = pack2(lo.z, lo.w);
                o.z = pack2(hi.x, hi.y); o.w = pack2(hi.z, hi.w);
                a[r] = __builtin_bit_cast(bf16x8, o);
            } else {
                a[r] = __builtin_bit_cast(bf16x8, binA[CVT_A ? 0 : kt][r]);
            }
        }
        // issue prefetch for kt+P
        if (kt + P < KITERS) issueA(kt + P);
        // 10 MFMAs off the resident panel
        #pragma unroll
        for (int c = 0; c < 5; ++c) {
            bf16x8 bb = __builtin_bit_cast(bf16x8, *reinterpret_cast<const uint4*>(
                &Bs[((kt * 10 + wc * 5 + c) << 9) + lane * 8]));
            acc[0][c] = __builtin_amdgcn_mfma_f32_16x16x32_bf16(a[0], bb, acc[0][c], 0, 0, 0);
            acc[1][c] = __builtin_amdgcn_mfma_f32_16x16x32_bf16(a[1], bb, acc[1][c], 0, 0, 0);
        }
    }

    // ---- epilogue: bias + act -> tiled C; C/D frag: col=l16, row=q*4+reg ----
    #pragma unroll
    for (int r = 0; r < 2; ++r) {
        int rowblk = rowblk0 + wr * 2 + r;
        #pragma unroll
        for (int c = 0; c < 5; ++c) {
            int n = (nb0 + wc * 5 + c) * 16 + l16;
            float bv = bias[n];
            #pragma unroll
            for (int reg = 0; reg < 4; ++reg) {
                float v = acc[r][c][reg] + bv;
                if (RELU) v = fmaxf(v, 0.f);
                int mrow = q * 4 + reg;
                size_t off = (((size_t)rowblk * kTC + (n >> 5)) << 9)
                           + (size_t)(((n >> 3) & 3) * 16 + mrow) * 8 + (n & 7);
                C[off] = f2bf(v);
            }
        }
    }
}

// ---------------------------------------------------------------------------
// flow_kernel v3: 4 lanes per row (lane sub owns head cols [8*sub, 8*sub+8)).
// Aligned 48-col u/w slots -> one uint4 per lane per vector, fully coalesced.
// Dots reduced across the 4-lane group via shfl_xor(1,2). No LDS, no spills.
// ---------------------------------------------------------------------------
__device__ inline void ld_group8(const ushort_t* hb, int g, float* dst) {
    uint4 v = *reinterpret_cast<const uint4*>(hb + ((g >> 2) << 9) + ((g & 3) << 7));
    unpack8(v, dst);
}

__global__ __launch_bounds__(256, 4)
void flow_kernel(const ushort_t* __restrict__ heads, const float* __restrict__ eps,
                 float* __restrict__ out, int Btot)
{
    const int tid = threadIdx.x;
    const int sub = tid & 3;
    const long row = (long)blockIdx.x * 64 + (tid >> 2);
    const ushort_t* hb = heads + (((size_t)(row >> 4) * KTH) << 9)
                               + (size_t)((row & 15) << 3);

    float z[8];
    float lp = 0.f;
    {
        float amu[8] = {0,0,0,0,0,0,0,0}, alv[8] = {0,0,0,0,0,0,0,0};
        if (sub < 3) {
            ld_group8(hb, sub, amu);
            ld_group8(hb, 3 + sub, alv);
        }
        float ep[8];
        #pragma unroll
        for (int c = 0; c < 8; ++c) {
            int i = sub * 8 + c;
            ep[c] = (i < 17) ? eps[row * 17 + i] : 0.f;
        }
        #pragma unroll
        for (int c = 0; c < 8; ++c) {
            float mu = fast_tanh(amu[c]);
            float lv = fast_tanh(alv[c]);
            z[c] = mu + __expf(lv) * ep[c];
            int i = sub * 8 + c;
            lp += (i < 17) ? (-0.5f * ep[c] * ep[c] - lv - 0.918938533f) : 0.f;
        }
    }

    float bv[16];
    ld_group8(hb, 6, &bv[0]);
    ld_group8(hb, 7, &bv[8]);

    float ldj = 0.f;
    #pragma unroll
    for (int k = 0; k < 15; ++k) {
        float au[8] = {0,0,0,0,0,0,0,0}, aw[8] = {0,0,0,0,0,0,0,0};
        if (sub < 3) {
            ld_group8(hb, 8 + 6 * k + sub, au);
            ld_group8(hb, 11 + 6 * k + sub, aw);
        }
        float uw = 0.f, w2 = 0.f, wz = 0.f;
        #pragma unroll
        for (int c = 0; c < 8; ++c) {
            uw += aw[c] * au[c];
            w2 += aw[c] * aw[c];
            wz += aw[c] * z[c];
        }
        uw += __shfl_xor(uw, 1); uw += __shfl_xor(uw, 2);
        w2 += __shfl_xor(w2, 1); w2 += __shfl_xor(w2, 2);
        wz += __shfl_xor(wz, 1); wz += __shfl_xor(wz, 2);

        float sp = (uw > 15.f) ? uw : __logf(1.f + __expf(uw));
        float m = sp - 1.f;                          // -1 + softplus(w.u)
        float coef = (m - uw) / fmaxf(w2, 1e-20f);
        float t = fast_tanh(wz + bv[k]);
        #pragma unroll
        for (int c = 0; c < 8; ++c)
            z[c] += (au[c] + coef * aw[c]) * t;
        float psi = m * (1.f - t * t);               // psi^T u_hat == m analytically
        ldj += __logf(fmaxf(fabsf(1.f + psi), 1e-30f));
    }

    lp += __shfl_xor(lp, 1); lp += __shfl_xor(lp, 2);
    #pragma unroll
    for (int c = 0; c < 8; ++c) {
        int i = sub * 8 + c;
        if (i < 17) out[row * 17 + i] = z[c];
    }
    float lpf = lp - ldj;
    if (sub == 0) {
        out[(long)Btot * 17 + row] = __expf(lpf);
        out[(long)Btot * 18 + row] = lpf;
    }
}

// ---------------------------------------------------------------------------
extern "C" void kernel_launch(void* const* d_in, const int* in_sizes, int n_in,
                              void* d_out, int out_size, void* d_ws, size_t ws_size,
                              hipStream_t stream)
{
    const float* x   = (const float*)d_in[0];
    const float* eps = (const float*)d_in[1];
    float* out = (float*)d_out;

    // ws layout (ushort units):
    //  [0, H2_US)                 h2' tiled (stride KTC2)
    //  [H2_US, H2_US+HEADS_US)    h1' tiled (stride KTC1) then heads tiled
    //                             (stride KTH) -- h1' dead by K3
    //  weights after + biases
    ushort_t* ws = (ushort_t*)d_ws;
    ushort_t* R_h2    = ws;
    ushort_t* R_h1    = ws + H2_US;
    ushort_t* R_heads = ws + H2_US;        // overlays h1'
    ushort_t* W1t = ws + H2_US + HEADS_US;
    ushort_t* W2t = W1t + SZ1;
    ushort_t* Wht = W2t + SZ2;
    float* b1p = (float*)(Wht + SZ3);
    float* b2p = b1p + 480;
    float* bHp = b2p + 320;

    const int packN = SZ1 + SZ2 + SZ3 + 1600;
    pack_kernel<<<(packN + 255) / 256, 256, 0, stream>>>(
        (const float*)d_in[2],  (const float*)d_in[4],
        (const float*)d_in[6],  (const float*)d_in[8],
        (const float*)d_in[10], (const float*)d_in[12], (const float*)d_in[14],
        (const float*)d_in[3],  (const float*)d_in[5],
        (const float*)d_in[7],  (const float*)d_in[9],
        (const float*)d_in[11], (const float*)d_in[13], (const float*)d_in[15],
        W1t, W2t, Wht, b1p, b2p, bHp);

    // K1: h1' = relu(x @ W1^T + b1), cvt fused.  M=65536 K=384 N=480
    gemm_bp<KT1, 3, true, true><<<3 * 512, 512, 0, stream>>>(
        nullptr, x, W1t, b1p, R_h1, 0, KTC1);
    // K2: h2' = relu(h1' @ W2^T + b2).           M=65536 K=416 N=320
    gemm_bp<KI2, 2, true, false><<<2 * 512, 512, 0, stream>>>(
        R_h1, nullptr, W2t, b2p, R_h2, KTC1, KTC2);
    // K3: heads = h2' @ Wh^T + bH.               M=65536 K=320 N=800
    gemm_bp<KI3, 5, false, false><<<5 * 512, 512, 0, stream>>>(
        R_h2, nullptr, Wht, bHp, R_heads, KTC2, KTH);
    // K4: planar flow + log-prob
    flow_kernel<<<B_ROWS / 64, 256, 0, stream>>>(R_heads, eps, out, B_ROWS);
}